// Round 1
// baseline (166.706 us; speedup 1.0000x reference)
//
#include <hip/hip_runtime.h>

#define KK 40        // N_RADIAL * N_ANGULAR
#define FEAT 16
#define NT 8
#define ODIM 32
#define VPB 64       // vertices per block
#define BLOCK 256

// csum[k] = sum_{r,a} interp_coeffs[r,a,k]
__global__ void csum_kernel(const float* __restrict__ ic, float* __restrict__ csum) {
    int k = threadIdx.x;
    if (k < KK) {
        float s = 0.f;
        #pragma unroll
        for (int ra = 0; ra < KK; ++ra) s += ic[ra * KK + k];
        csum[k] = s;
    }
}

__global__ __launch_bounds__(BLOCK, 2) void conv_kernel(
    const float* __restrict__ mesh,   // [N,16]
    const float* __restrict__ bw,     // [N,40,3]
    const float* __restrict__ W,      // [8,32,16]
    const float* __restrict__ bias,   // [8,32]
    const int*   __restrict__ bi,     // [N,40,3]
    const float* __restrict__ csum,   // [40]
    float*       __restrict__ out,    // [N,32]
    int n)
{
    __shared__ float s_sig[VPB][FEAT + 1];   // +1 pad: stride 17 dwords, conflict-free
    __shared__ float s_cs[KK];

    const int tid = threadIdx.x;
    if (tid < KK) s_cs[tid] = csum[tid];
    __syncthreads();

    // ---------------- Phase 1: gather + interp ----------------
    // 4 lanes per vertex; lane q handles feature quad q (float4).
    {
        const int vloc = tid >> 2;
        const int q    = tid & 3;
        const int vg   = blockIdx.x * VPB + vloc;
        float a0 = 0.f, a1 = 0.f, a2 = 0.f, a3 = 0.f;
        if (vg < n) {
            const float* bwp = bw + (size_t)vg * (KK * 3);
            const int*   bip = bi + (size_t)vg * (KK * 3);
            #pragma unroll 4
            for (int k = 0; k < KK; ++k) {
                const float ck = s_cs[k];
                #pragma unroll
                for (int j = 0; j < 3; ++j) {
                    const float w   = ck * bwp[k * 3 + j];
                    const int   idx = bip[k * 3 + j];
                    const float4 r  = *((const float4*)(mesh + (size_t)idx * FEAT) + q);
                    a0 = fmaf(w, r.x, a0);
                    a1 = fmaf(w, r.y, a1);
                    a2 = fmaf(w, r.z, a2);
                    a3 = fmaf(w, r.w, a3);
                }
            }
        }
        s_sig[vloc][q * 4 + 0] = a0;
        s_sig[vloc][q * 4 + 1] = a1;
        s_sig[vloc][q * 4 + 2] = a2;
        s_sig[vloc][q * 4 + 3] = a3;
    }
    __syncthreads();

    // ---------------- Phase 2: fold (W @ s, relu, sum over t) ----------------
    // lane = vertex; wave w owns outputs o in [8w, 8w+8) for ALL templates.
    {
        const int lane = tid & 63;
        const int wave = __builtin_amdgcn_readfirstlane(tid >> 6);  // 0..3, SGPR
        const int vg2  = blockIdx.x * VPB + lane;

        float s[FEAT];
        #pragma unroll
        for (int f = 0; f < FEAT; ++f) s[f] = s_sig[lane][f];

        float oacc[8];
        #pragma unroll
        for (int oi = 0; oi < 8; ++oi) oacc[oi] = 0.f;

        #pragma unroll 2
        for (int t = 0; t < NT; ++t) {
            #pragma unroll
            for (int oi = 0; oi < 8; ++oi) {
                const int o = wave * 8 + oi;
                float pre = bias[t * ODIM + o];             // uniform -> s_load
                const float* wrow = W + ((size_t)t * ODIM + o) * FEAT;  // uniform
                #pragma unroll
                for (int f = 0; f < FEAT; ++f)
                    pre = fmaf(wrow[f], s[f], pre);
                oacc[oi] += fmaxf(pre, 0.f);
            }
        }

        if (vg2 < n) {
            float* op = out + (size_t)vg2 * ODIM + wave * 8;
            float4 v0 = make_float4(oacc[0], oacc[1], oacc[2], oacc[3]);
            float4 v1 = make_float4(oacc[4], oacc[5], oacc[6], oacc[7]);
            *((float4*)op)     = v0;
            *((float4*)(op+4)) = v1;
        }
    }
}

extern "C" void kernel_launch(void* const* d_in, const int* in_sizes, int n_in,
                              void* d_out, int out_size, void* d_ws, size_t ws_size,
                              hipStream_t stream) {
    const float* mesh = (const float*)d_in[0];
    const float* bw   = (const float*)d_in[1];
    const float* ic   = (const float*)d_in[2];
    const float* W    = (const float*)d_in[3];
    const float* bias = (const float*)d_in[4];
    const int*   bi   = (const int*)d_in[5];
    float* out = (float*)d_out;
    float* csum = (float*)d_ws;

    const int n = in_sizes[0] / FEAT;   // N_VERTS

    csum_kernel<<<1, 64, 0, stream>>>(ic, csum);

    const int blocks = (n + VPB - 1) / VPB;
    conv_kernel<<<blocks, BLOCK, 0, stream>>>(mesh, bw, W, bias, bi, csum, out, n);
}